// Round 12
// baseline (47.640 us; speedup 1.0000x reference)
//
#include <hip/hip_runtime.h>
#include <hip/hip_bf16.h>

#define N_ 8192
#define D_ 256
#define NTB 4160   // Σ_{I=0..127} (64 - (I>>1)) ; 4160 = 8*520
#define LRB 128    // lastrow blocks folded into simloss grid

typedef float f32x4 __attribute__((ext_vector_type(4)));

// ws layout (doubles): [0..95] = 32 slots x {pos_cnt, pos_sim_sum, neg_sim_sum}
//                      [128..2175] = 512 lastrow wave-slots x {lp_s,lp_c,ln_s,ln_c}
// Xf8 (fp8 e4m3, FRAGMENT-MAJOR) at ws+32768, 2 MB:
//   addr(g, kt, fr, b) = g*4096 + kt*512 + fr*32 + b
//   holds row 16g+fr, element k = kt*32 + b.
// A wave's MFMA fragment (group g, K-step kt) = bytes [g*4096+kt*512, +512),
// lane (fr=lane&15, slv=lane>>4) reads 8 B at fr*32+slv*8 -> one fully
// coalesced 512 B global_load_dwordx2 per fragment. No LDS, no barriers.

// ---------------- prep: f32 -> fp8 fragment-major (+ zero slot accumulators) ----
__global__ void prep_kernel(const float* __restrict__ X,
                            unsigned char* __restrict__ Xf8,
                            double* __restrict__ accd) {
  if (blockIdx.x == 0 && threadIdx.x < 96) accd[threadIdx.x] = 0.0;
  int c = blockIdx.x * 256 + threadIdx.x;  // 131072 chunks of 16 B
  int g = c >> 8, rem = c & 255;
  int kt = rem >> 5, rem2 = rem & 31;
  int fr = rem2 >> 1, h = rem2 & 1;
  const float* src = X + (size_t)(g * 16 + fr) * D_ + kt * 32 + h * 16;
  float4 v0 = *(const float4*)(src);
  float4 v1 = *(const float4*)(src + 4);
  float4 v2 = *(const float4*)(src + 8);
  float4 v3 = *(const float4*)(src + 12);
  int4 d;
  d.x = __builtin_amdgcn_cvt_pk_fp8_f32(v0.x, v0.y, 0, false);
  d.x = __builtin_amdgcn_cvt_pk_fp8_f32(v0.z, v0.w, d.x, true);
  d.y = __builtin_amdgcn_cvt_pk_fp8_f32(v1.x, v1.y, 0, false);
  d.y = __builtin_amdgcn_cvt_pk_fp8_f32(v1.z, v1.w, d.y, true);
  d.z = __builtin_amdgcn_cvt_pk_fp8_f32(v2.x, v2.y, 0, false);
  d.z = __builtin_amdgcn_cvt_pk_fp8_f32(v2.z, v2.w, d.z, true);
  d.w = __builtin_amdgcn_cvt_pk_fp8_f32(v3.x, v3.y, 0, false);
  d.w = __builtin_amdgcn_cvt_pk_fp8_f32(v3.z, v3.w, d.w, true);
  *(int4*)(Xf8 + (size_t)c * 16) = d;  // fully coalesced linear store
}

// offset(I) = number of (64x128)-blocks before row-band I
#define OFFI(I) (64 * (I) - ((I) * (I)-2 * (I) + ((I)&1)) / 4)

// ------- barrier-free fused fp8 GEMM + masked reduction (+ folded lastrow) -------
__global__ __launch_bounds__(256, 4) void simloss_kernel(
    const unsigned char* __restrict__ Xf8, const float* __restrict__ X,
    const int* __restrict__ tg, double* __restrict__ accd) {
  const int tid = threadIdx.x;
  const int lane = tid & 63, wv = tid >> 6;

  if (blockIdx.x < LRB) {
    // ---- last-row stats in fp64 (proven absmax-0 path), race-free slots ----
    int lb = blockIdx.x;
    const float4* xl = (const float4*)(X + (size_t)(N_ - 1) * D_);
    float4 a = xl[lane];
    int tlast = tg[N_ - 1];
    double lp = 0, lpc = 0, ln = 0, lnc = 0;
    for (int cc = 0; cc < 16; ++cc) {
      int j = lb * 64 + wv * 16 + cc;
      float4 bq = ((const float4*)(X + (size_t)j * D_))[lane];
      double s = (double)a.x * bq.x + (double)a.y * bq.y +
                 (double)a.z * bq.z + (double)a.w * bq.w;
#pragma unroll
      for (int off = 32; off; off >>= 1) s += __shfl_down(s, off);
      if (lane == 0) {
        float sf = (float)s;
        bool same = (tg[j] == tlast);
        if (same && sf < 1.0f) { lp += sf; lpc += 1.0; }
        if (!same) { ln += sf; lnc += 1.0; }
      }
    }
    if (lane == 0) {
      double* slot = accd + 128 + (size_t)(lb * 4 + wv) * 4;
      slot[0] = lp; slot[1] = lpc; slot[2] = ln; slot[3] = lnc;
    }
    return;
  }

  // ---- XCD-chunked bijective swizzle over the 4160 GEMM blocks ----
  const int t0 = blockIdx.x - LRB;
  const int t = (t0 & 7) * (NTB / 8) + (t0 >> 3);

  // ---- decode (I, K): block covers rows [64I,64I+64) x cols [128K,128K+128) ----
  float disc = 16384.0f - 4.0f * (float)t;
  int I = (int)(128.0f - sqrtf(disc > 0.0f ? disc : 0.0f));
  if (I < 0) I = 0;
  if (I > 127) I = 127;
  while (I < 127 && OFFI(I + 1) <= t) ++I;
  while (I > 0 && OFFI(I) > t) --I;
  const int K = (I >> 1) + (t - OFFI(I));
  const int J = K * 4 + wv;          // this wave's 32-col tile
  const int rowA0 = I * 64, colB0 = J * 32;

  // ---- fragment base pointers (base + imm offsets only in the loop) ----
  const int fr = lane & 15, slv = lane >> 4;
  const int lo = fr * 32 + slv * 8;
  const unsigned char* pA[4];
  const unsigned char* pB[2];
#pragma unroll
  for (int m = 0; m < 4; ++m) pA[m] = Xf8 + (size_t)(I * 4 + m) * 4096 + lo;
#pragma unroll
  for (int n = 0; n < 2; ++n) pB[n] = Xf8 + (size_t)(J * 2 + n) * 4096 + lo;

  f32x4 acc[4][2] = {};
  long fa[8][4], fb[8][2];

  // prologue: preload K-steps 0..3 (depth-4 pipeline)
#pragma unroll
  for (int kt = 0; kt < 4; ++kt) {
#pragma unroll
    for (int m = 0; m < 4; ++m) fa[kt][m] = *(const long*)(pA[m] + kt * 512);
#pragma unroll
    for (int n = 0; n < 2; ++n) fb[kt][n] = *(const long*)(pB[n] + kt * 512);
  }

#pragma unroll
  for (int kt = 0; kt < 8; ++kt) {
    if (kt + 4 < 8) {  // issue step kt+4 loads ahead of consuming step kt
#pragma unroll
      for (int m = 0; m < 4; ++m) fa[kt + 4][m] = *(const long*)(pA[m] + (kt + 4) * 512);
#pragma unroll
      for (int n = 0; n < 2; ++n) fb[kt + 4][n] = *(const long*)(pB[n] + (kt + 4) * 512);
    }
#pragma unroll
    for (int m = 0; m < 4; ++m)
#pragma unroll
      for (int n = 0; n < 2; ++n)
        acc[m][n] = __builtin_amdgcn_mfma_f32_16x16x32_fp8_fp8(fa[kt][m], fb[kt][n],
                                                               acc[m][n], 0, 0, 0);
  }

  // ---- epilogue: C/D layout col=lane&15, row=(lane>>4)*4+reg (dtype-indep) ----
  // Triangle weight per element: w = 2 if r<c else 0 (diagonal contributes 0;
  // below-diagonal parts of straddling tiles are mirrors -> skip).
  const int cRow = slv * 4, cCol = fr;
  int tj[2], ti[4][4];
#pragma unroll
  for (int n = 0; n < 2; ++n) tj[n] = tg[colB0 + n * 16 + cCol];
#pragma unroll
  for (int m = 0; m < 4; ++m)
#pragma unroll
    for (int r = 0; r < 4; ++r) ti[m][r] = tg[rowA0 + m * 16 + cRow + r];

  float pc = 0.f, ps = 0.f, ns = 0.f;
#pragma unroll
  for (int m = 0; m < 4; ++m)
#pragma unroll
    for (int n = 0; n < 2; ++n)
#pragma unroll
      for (int r = 0; r < 4; ++r) {
        float s = acc[m][n][r];
        int rr = rowA0 + m * 16 + cRow + r;
        int cc = colB0 + n * 16 + cCol;
        float w = (rr < cc) ? 2.0f : 0.0f;
        bool same = (ti[m][r] == tj[n]);
        if (same & (s < 0.9f)) { pc += w; ps += w * s; }
        if ((!same) & (s > 0.5f)) { ns += w * s; }
      }

  // ---- block reduction + per-slot atomics ----
#pragma unroll
  for (int off = 32; off > 0; off >>= 1) {
    pc += __shfl_down(pc, off);
    ps += __shfl_down(ps, off);
    ns += __shfl_down(ns, off);
  }
  __shared__ float red[12];
  if (lane == 0) { red[0 + wv] = pc; red[4 + wv] = ps; red[8 + wv] = ns; }
  __syncthreads();
  if (tid == 0) {
    double* slot = accd + (blockIdx.x & 31) * 3;
    atomicAdd(&slot[0], (double)(red[0] + red[1] + red[2] + red[3]));
    atomicAdd(&slot[1], (double)(red[4] + red[5] + red[6] + red[7]));
    atomicAdd(&slot[2], (double)(red[8] + red[9] + red[10] + red[11]));
  }
}

// ---------------- finalize (single wave) ----------------
__global__ void finalize_kernel(const double* __restrict__ accd, float* __restrict__ out) {
  int l = threadIdx.x;  // 64 threads
  double lp = 0, lpc = 0, ln = 0, lnc = 0;
  for (int q = l; q < 512; q += 64) {
    const double* s = accd + 128 + (size_t)q * 4;
    lp += s[0]; lpc += s[1]; ln += s[2]; lnc += s[3];
  }
  double pc = 0, ps = 0, ns = 0;
  if (l < 32) { pc = accd[l * 3]; ps = accd[l * 3 + 1]; ns = accd[l * 3 + 2]; }
#pragma unroll
  for (int off = 32; off > 0; off >>= 1) {
    lp += __shfl_down(lp, off);  lpc += __shfl_down(lpc, off);
    ln += __shfl_down(ln, off);  lnc += __shfl_down(lnc, off);
    pc += __shfl_down(pc, off);  ps += __shfl_down(ps, off);
    ns += __shfl_down(ns, off);
  }
  if (l == 0) {
    out[0] = (float)((pc - ps + ns) / (double)N_);
    out[1] = 0.0f;  // prec: reference never increments c
    out[2] = (float)(lp / fmax(lpc, 1.0));
    out[3] = (float)(ln / fmax(lnc, 1.0));
  }
}

extern "C" void kernel_launch(void* const* d_in, const int* in_sizes, int n_in,
                              void* d_out, int out_size, void* d_ws, size_t ws_size,
                              hipStream_t stream) {
  const float* X = (const float*)d_in[0];
  const int* tg = (const int*)d_in[1];
  float* out = (float*)d_out;
  double* accd = (double*)d_ws;
  unsigned char* Xf8 = (unsigned char*)d_ws + 32768;

  prep_kernel<<<512, 256, 0, stream>>>(X, Xf8, accd);
  simloss_kernel<<<LRB + NTB, 256, 0, stream>>>(Xf8, X, tg, accd);
  finalize_kernel<<<1, 64, 0, stream>>>(accd, out);
}